// Round 12
// baseline (39.698 us; speedup 1.0000x reference)
//
#include <hip/hip_runtime.h>
#include <hip/hip_fp16.h>

#define NROWS 2048
#define MCOLS 2048
#define DDIM  64
#define BT    128               // k1 big tile (rows & cols)
#define NBT   (NROWS / BT)      // 16 k1 tiles per dim
#define TILE2 64                // k2 tile
#define NT2   (NROWS / TILE2)   // 32 k2 tiles per dim

// No-max softmax: s row/col maxima ~ -50 (64-d Gaussian L1), exp(-58)=6e-26
// >> f32 denormal; 1/sum <= 5e34 < f32 max. exp(s) directly, no max pass.

// ============================================================================
// K1: 128x128 tile, 8x8 per thread. Computes s tile, rounds to fp16 (s~),
// stores s~ (8 MiB), accumulates per-tile exp-sums for rows & cols
// (on the rounded s~, so k2 is bit-consistent).
//   rs_part: [NBT][NROWS]   cs_part: [NBT][MCOLS]
// ============================================================================
__global__ __launch_bounds__(256) void k1_dist(
    const float* __restrict__ zx, const float* __restrict__ zy,
    __half* __restrict__ s_out,
    float* __restrict__ rs_part, float* __restrict__ cs_part)
{
  __shared__ float sX[DDIM][BT];   // [d][i]  32 KB
  __shared__ float sY[DDIM][BT];   // [d][j]  32 KB
  __shared__ float csw[4][BT];     // 2 KB

  const int bi = blockIdx.y, bj = blockIdx.x;
  const int t  = threadIdx.x;
  const int lid = t & 63, wv = t >> 6;
  const int i0 = (t >> 4) << 3;   // 0..120, 8 rows/thread
  const int j0 = (t & 15) << 3;   // 0..120, 8 cols/thread

  // ---- stage both tiles transposed: 2 threads/row, 32 d each ----
  {
    int r = t & 127, half = t >> 7;
    const float* zxp = zx + (size_t)(bi * BT + r) * DDIM + half * 32;
    const float* zyp = zy + (size_t)(bj * BT + r) * DDIM + half * 32;
#pragma unroll
    for (int q = 0; q < 8; ++q) {
      float4 xv = *(const float4*)(zxp + q * 4);
      float4 yv = *(const float4*)(zyp + q * 4);
      int d = half * 32 + q * 4;
      sX[d+0][r]=xv.x; sX[d+1][r]=xv.y; sX[d+2][r]=xv.z; sX[d+3][r]=xv.w;
      sY[d+0][r]=yv.x; sY[d+1][r]=yv.y; sY[d+2][r]=yv.z; sY[d+3][r]=yv.w;
    }
  }
  __syncthreads();

  // ---- distances: 8x8 acc, 4 ds_read_b128 + 128 VALU per d ----
  float acc[8][8] = {{0.f}};
#pragma unroll 4
  for (int d = 0; d < DDIM; ++d) {
    float4 x0 = *(const float4*)&sX[d][i0];
    float4 x1 = *(const float4*)&sX[d][i0 + 4];
    float4 y0 = *(const float4*)&sY[d][j0];
    float4 y1 = *(const float4*)&sY[d][j0 + 4];
    float xr[8] = {x0.x, x0.y, x0.z, x0.w, x1.x, x1.y, x1.z, x1.w};
    float yc[8] = {y0.x, y0.y, y0.z, y0.w, y1.x, y1.y, y1.z, y1.w};
#pragma unroll
    for (int a = 0; a < 8; ++a)
#pragma unroll
      for (int b = 0; b < 8; ++b)
        acc[a][b] += fabsf(xr[a] - yc[b]);
  }

  // ---- per row: round to fp16, store s~, exp, accumulate stats ----
  float es[8];                 // row exp-sums (this thread's 8 cols)
  float ce[8] = {0.f};         // col exp-sums (this thread's 8 rows)
#pragma unroll
  for (int a = 0; a < 8; ++a) {
    __half2 h[4];
#pragma unroll
    for (int p = 0; p < 4; ++p)
      h[p] = __floats2half2_rn(-acc[a][2*p], -acc[a][2*p+1]);
    uint4 u;
    u.x = *(const unsigned*)&h[0];
    u.y = *(const unsigned*)&h[1];
    u.z = *(const unsigned*)&h[2];
    u.w = *(const unsigned*)&h[3];
    *(uint4*)(s_out + (size_t)(bi * BT + i0 + a) * MCOLS + bj * BT + j0) = u;
    float rowsum = 0.f;
#pragma unroll
    for (int p = 0; p < 4; ++p) {
      float2 f = __half22float2(h[p]);
      float e0 = __expf(f.x), e1 = __expf(f.y);
      rowsum += e0 + e1;
      ce[2*p]   += e0;
      ce[2*p+1] += e1;
    }
    es[a] = rowsum;
  }

  // ---- row exp-sums: 16 j-lanes (bits 0..3) cover one tile-row ----
#pragma unroll
  for (int off = 1; off <= 8; off <<= 1)
#pragma unroll
    for (int a = 0; a < 8; ++a)
      es[a] += __shfl_xor(es[a], off);
  if ((lid & 15) == 0) {
#pragma unroll
    for (int a = 0; a < 8; ++a)
      rs_part[bj * NROWS + bi * BT + i0 + a] = es[a];
  }

  // ---- col exp-sums: lane bits 4..5 (4 i-groups/wave), then LDS x 4 waves --
#pragma unroll
  for (int off = 16; off <= 32; off <<= 1)
#pragma unroll
    for (int b = 0; b < 8; ++b)
      ce[b] += __shfl_xor(ce[b], off);
  if (lid < 16) {
#pragma unroll
    for (int b = 0; b < 8; ++b)
      csw[wv][lid * 8 + b] = ce[b];
  }
  __syncthreads();
  if (t < BT) {
    int j = t;
    cs_part[bi * MCOLS + bj * BT + j] =
        (csw[0][j] + csw[1][j]) + (csw[2][j] + csw[3][j]);
  }
}

// ============================================================================
// K2: per-block stats-sum (L2/L3-hot partials) + reload s~ tile + combine
//     -> one (pn,pd) pair per block. No atomics, no fences.
// ============================================================================
__global__ __launch_bounds__(256) void k2_combine(
    const __half* __restrict__ s_in,
    const float* __restrict__ rs_part, const float* __restrict__ cs_part,
    float* __restrict__ part /* [NT2*NT2][2] */)
{
  __shared__ float l_rinv[TILE2];
  __shared__ float l_cinv[TILE2];
  __shared__ float red[8];

  int bi = blockIdx.y, bj = blockIdx.x;
  int t  = threadIdx.x;
  int lid = t & 63, wv = t >> 6;
  int i0 = (t >> 4) << 2, j0 = (t & 15) << 2;

  // ---- plain sums of 16 partials for the 64 rows + 64 cols we need ----
  if (t < 64) {
    int i = bi * TILE2 + t;
    float S = 0.f;
#pragma unroll
    for (int tj = 0; tj < NBT; ++tj) S += rs_part[tj * NROWS + i];
    l_rinv[t] = 1.f / S;
  } else if (t < 128) {
    int c = t - 64;
    int j = bj * TILE2 + c;
    float S = 0.f;
#pragma unroll
    for (int ti = 0; ti < NBT; ++ti) S += cs_part[ti * MCOLS + j];
    l_cinv[c] = 1.f / S;
  }
  __syncthreads();

  // ---- reload s~ tile and combine (one exp per entry, shared by a & b) ----
  float sv[4][4];
  {
    const __half* base = s_in + (size_t)(bi * TILE2 + i0) * MCOLS + bj * TILE2 + j0;
#pragma unroll
    for (int a = 0; a < 4; ++a) {
      uint2 u = *(const uint2*)(base + (size_t)a * MCOLS);
      __half2 h01 = *(const __half2*)&u.x;
      __half2 h23 = *(const __half2*)&u.y;
      float2 f01 = __half22float2(h01), f23 = __half22float2(h23);
      sv[a][0] = f01.x; sv[a][1] = f01.y; sv[a][2] = f23.x; sv[a][3] = f23.y;
    }
  }
  float rv[4], cv[4];
#pragma unroll
  for (int a = 0; a < 4; ++a) rv[a] = l_rinv[i0 + a];
#pragma unroll
  for (int b = 0; b < 4; ++b) cv[b] = l_cinv[j0 + b];

  float pn = 0.f, pd = 0.f;
#pragma unroll
  for (int a = 0; a < 4; ++a)
#pragma unroll
    for (int b = 0; b < 4; ++b) {
      float E  = __expf(sv[a][b]);
      float av = E * rv[a];
      float bv = E * cv[b];
      float w  = av + bv - av * bv;
      pn += w * sv[a][b];
      pd += w;
    }
#pragma unroll
  for (int off = 1; off <= 32; off <<= 1) {
    pn += __shfl_xor(pn, off);
    pd += __shfl_xor(pd, off);
  }
  if (lid == 0) { red[wv * 2] = pn; red[wv * 2 + 1] = pd; }
  __syncthreads();
  if (t == 0) {
    int bid = bi * NT2 + bj;
    float2 p;
    p.x = red[0] + red[2] + red[4] + red[6];
    p.y = red[1] + red[3] + red[5] + red[7];
    *(float2*)(part + bid * 2) = p;
  }
}

// ============================================================================
// K3: deterministic reduce of 1024 (pn,pd) pairs -> out scalar.
// ============================================================================
__global__ __launch_bounds__(256) void k3_out(
    const float* __restrict__ part, float* __restrict__ out)
{
  int t = threadIdx.x;
  float pn = 0.f, pd = 0.f;
#pragma unroll
  for (int k = t; k < NT2 * NT2; k += 256) {
    float2 v = *(const float2*)(part + k * 2);
    pn += v.x;
    pd += v.y;
  }
#pragma unroll
  for (int off = 1; off <= 32; off <<= 1) {
    pn += __shfl_xor(pn, off);
    pd += __shfl_xor(pd, off);
  }
  __shared__ float red[8];
  if ((t & 63) == 0) { red[(t >> 6) * 2] = pn; red[(t >> 6) * 2 + 1] = pd; }
  __syncthreads();
  if (t == 0) {
    float n = red[0] + red[2] + red[4] + red[6];
    float d = red[1] + red[3] + red[5] + red[7];
    out[0] = n / d;
  }
}

extern "C" void kernel_launch(void* const* d_in, const int* in_sizes, int n_in,
                              void* d_out, int out_size, void* d_ws, size_t ws_size,
                              hipStream_t stream)
{
  const float* zx = (const float*)d_in[0];
  const float* zy = (const float*)d_in[1];
  float* out = (float*)d_out;

  char* ws = (char*)d_ws;
  float* part    = (float*)(ws + 0);            // 1024*2 f32 = 8 KB
  float* rs_part = (float*)(ws + (64  << 10));  // [16][2048] f32 = 128 KB
  float* cs_part = (float*)(ws + (320 << 10));  // [16][2048] f32 = 128 KB
  __half* s_buf  = (__half*)(ws + (576 << 10)); // 8 MiB fp16

  k1_dist   <<<dim3(NBT, NBT), dim3(256), 0, stream>>>(zx, zy, s_buf,
                rs_part, cs_part);
  k2_combine<<<dim3(NT2, NT2), dim3(256), 0, stream>>>(s_buf,
                rs_part, cs_part, part);
  k3_out    <<<dim3(1), dim3(256), 0, stream>>>(part, out);
}

// Round 13
// 30.790 us; speedup vs baseline: 1.2893x; 1.2893x over previous
//
#include <hip/hip_runtime.h>
#include <hip/hip_fp16.h>

#define NROWS 2048
#define MCOLS 2048
#define DDIM  64
#define NDP   (DDIM / 2)   // 32 packed d-pairs
#define TILE  64
#define NTI   32
#define NTJ   32

// No-max softmax: s row/col maxima ~ -50 (64-d Gaussian L1), exp(-58)=6e-26
// >> f32 denormal; 1/sum <= 5e34 < f32 max. exp(s) directly, no max pass.
// Distances accumulated in packed fp16 (RMS err ~0.1 in s; unbiased; c error
// second-order, far under threshold). s~ = fp16 of the accumulated value is
// used for BOTH k1 stats and k2 combine -> bit-consistent softmax.

// ============================================================================
// K1: 64x64 tile, 4x4 per thread, packed-fp16 inner loop over 32 d-pairs.
// Stores s~ (8 MiB) + per-tile row/col exp-sum partials.
//   rs_part: [NTJ][NROWS]   cs_part: [NTI][MCOLS]
// ============================================================================
__global__ __launch_bounds__(256) void k1_dist(
    const float* __restrict__ zx, const float* __restrict__ zy,
    __half* __restrict__ s_out,
    float* __restrict__ rs_part, float* __restrict__ cs_part)
{
  __shared__ __half2 sX[NDP][TILE];   // [dp][i]  8 KB
  __shared__ __half2 sY[NDP][TILE];   // [dp][j]  8 KB
  __shared__ float   csw[4][TILE];    // 1 KB

  const int bi = blockIdx.y, bj = blockIdx.x;
  const int t  = threadIdx.x;
  const int lid = t & 63, wv = t >> 6;
  const int i0 = (t >> 4) << 2;
  const int j0 = (t & 15) << 2;

  // ---- stage (transposed, fp16-packed d-pairs) ----
  {
    int r  = t & 63;
    int d0 = (t >> 6) << 2;
    const float* zxp = zx + (size_t)(bi * TILE + r) * DDIM;
    const float* zyp = zy + (size_t)(bj * TILE + r) * DDIM;
#pragma unroll
    for (int q = 0; q < 4; ++q) {
      int d = d0 + 16 * q;
      float4 xv = *(const float4*)(zxp + d);
      float4 yv = *(const float4*)(zyp + d);
      sX[(d >> 1) + 0][r] = __floats2half2_rn(xv.x, xv.y);
      sX[(d >> 1) + 1][r] = __floats2half2_rn(xv.z, xv.w);
      sY[(d >> 1) + 0][r] = __floats2half2_rn(yv.x, yv.y);
      sY[(d >> 1) + 1][r] = __floats2half2_rn(yv.z, yv.w);
    }
  }
  __syncthreads();

  // ---- distances: packed fp16, 2 ds_read_b128 + 48 pk-VALU per d-pair ----
  __half2 acc2[4][4];
#pragma unroll
  for (int a = 0; a < 4; ++a)
#pragma unroll
    for (int b = 0; b < 4; ++b)
      acc2[a][b] = __floats2half2_rn(0.f, 0.f);

#pragma unroll 8
  for (int dp = 0; dp < NDP; ++dp) {
    uint4 ux = *(const uint4*)&sX[dp][i0];
    uint4 uy = *(const uint4*)&sY[dp][j0];
    __half2 xr[4] = { *(const __half2*)&ux.x, *(const __half2*)&ux.y,
                      *(const __half2*)&ux.z, *(const __half2*)&ux.w };
    __half2 yc[4] = { *(const __half2*)&uy.x, *(const __half2*)&uy.y,
                      *(const __half2*)&uy.z, *(const __half2*)&uy.w };
#pragma unroll
    for (int a = 0; a < 4; ++a)
#pragma unroll
      for (int b = 0; b < 4; ++b)
        acc2[a][b] = __hadd2(acc2[a][b], __habs2(__hsub2(xr[a], yc[b])));
  }

  // ---- s~ = -(lo+hi) in fp16; store; exp for stats ----
  float E[4][4];
#pragma unroll
  for (int a = 0; a < 4; ++a) {
    __half sh[4];
#pragma unroll
    for (int b = 0; b < 4; ++b) {
      sh[b] = __hneg(__hadd(__low2half(acc2[a][b]), __high2half(acc2[a][b])));
      E[a][b] = __expf(__half2float(sh[b]));
    }
    __half2 p01 = __halves2half2(sh[0], sh[1]);
    __half2 p23 = __halves2half2(sh[2], sh[3]);
    uint2 u;
    u.x = *(const unsigned*)&p01;
    u.y = *(const unsigned*)&p23;
    *(uint2*)(s_out + (size_t)(bi * TILE + i0 + a) * MCOLS + bj * TILE + j0) = u;
  }

  // ---- row exp-sums: 16 j-lanes (bits 0..3) cover one tile-row ----
  {
    float es[4];
#pragma unroll
    for (int a = 0; a < 4; ++a)
      es[a] = (E[a][0] + E[a][1]) + (E[a][2] + E[a][3]);
#pragma unroll
    for (int off = 1; off <= 8; off <<= 1)
#pragma unroll
      for (int a = 0; a < 4; ++a)
        es[a] += __shfl_xor(es[a], off);
    if ((lid & 15) == 0) {
#pragma unroll
      for (int a = 0; a < 4; ++a)
        rs_part[bj * NROWS + bi * TILE + i0 + a] = es[a];
    }
  }

  // ---- col exp-sums: lane bits 4..5, then LDS across 4 waves ----
  {
    float ce[4];
#pragma unroll
    for (int b = 0; b < 4; ++b)
      ce[b] = (E[0][b] + E[1][b]) + (E[2][b] + E[3][b]);
#pragma unroll
    for (int off = 16; off <= 32; off <<= 1)
#pragma unroll
      for (int b = 0; b < 4; ++b)
        ce[b] += __shfl_xor(ce[b], off);
    if (lid < 16) {
#pragma unroll
      for (int b = 0; b < 4; ++b)
        csw[wv][lid * 4 + b] = ce[b];
    }
    __syncthreads();
    if (t < TILE) {
      int j = t;
      cs_part[bi * MCOLS + bj * TILE + j] =
          (csw[0][j] + csw[1][j]) + (csw[2][j] + csw[3][j]);
    }
  }
}

// ============================================================================
// K2: per-block stats-sum (L2/L3-hot partials) + reload s~ tile + combine
//     -> one (pn,pd) pair per block. No atomics, no fences. (R11-identical)
// ============================================================================
__global__ __launch_bounds__(256) void k2_combine(
    const __half* __restrict__ s_in,
    const float* __restrict__ rs_part, const float* __restrict__ cs_part,
    float* __restrict__ part /* [NTI*NTJ][2] */)
{
  __shared__ float l_rinv[TILE];
  __shared__ float l_cinv[TILE];
  __shared__ float red[8];

  int bi = blockIdx.y, bj = blockIdx.x;
  int t  = threadIdx.x;
  int lid = t & 63, wv = t >> 6;
  int i0 = (t >> 4) << 2, j0 = (t & 15) << 2;

  if (t < 64) {
    int i = bi * TILE + t;
    float S = 0.f;
#pragma unroll
    for (int tj = 0; tj < NTJ; ++tj) S += rs_part[tj * NROWS + i];
    l_rinv[t] = 1.f / S;
  } else if (t < 128) {
    int c = t - 64;
    int j = bj * TILE + c;
    float S = 0.f;
#pragma unroll
    for (int ti = 0; ti < NTI; ++ti) S += cs_part[ti * MCOLS + j];
    l_cinv[c] = 1.f / S;
  }
  __syncthreads();

  float sv[4][4];
  {
    const __half* base = s_in + (size_t)(bi * TILE + i0) * MCOLS + bj * TILE + j0;
#pragma unroll
    for (int a = 0; a < 4; ++a) {
      uint2 u = *(const uint2*)(base + (size_t)a * MCOLS);
      __half2 h01 = *(const __half2*)&u.x;
      __half2 h23 = *(const __half2*)&u.y;
      float2 f01 = __half22float2(h01), f23 = __half22float2(h23);
      sv[a][0] = f01.x; sv[a][1] = f01.y; sv[a][2] = f23.x; sv[a][3] = f23.y;
    }
  }
  float rv[4], cv[4];
#pragma unroll
  for (int a = 0; a < 4; ++a) rv[a] = l_rinv[i0 + a];
#pragma unroll
  for (int b = 0; b < 4; ++b) cv[b] = l_cinv[j0 + b];

  float pn = 0.f, pd = 0.f;
#pragma unroll
  for (int a = 0; a < 4; ++a)
#pragma unroll
    for (int b = 0; b < 4; ++b) {
      float E  = __expf(sv[a][b]);
      float av = E * rv[a];
      float bv = E * cv[b];
      float w  = av + bv - av * bv;
      pn += w * sv[a][b];
      pd += w;
    }
#pragma unroll
  for (int off = 1; off <= 32; off <<= 1) {
    pn += __shfl_xor(pn, off);
    pd += __shfl_xor(pd, off);
  }
  if (lid == 0) { red[wv * 2] = pn; red[wv * 2 + 1] = pd; }
  __syncthreads();
  if (t == 0) {
    int bid = bi * NTJ + bj;
    float2 p;
    p.x = red[0] + red[2] + red[4] + red[6];
    p.y = red[1] + red[3] + red[5] + red[7];
    *(float2*)(part + bid * 2) = p;
  }
}

// ============================================================================
// K3: deterministic reduce of 1024 (pn,pd) pairs -> out scalar.
// ============================================================================
__global__ __launch_bounds__(256) void k3_out(
    const float* __restrict__ part, float* __restrict__ out)
{
  int t = threadIdx.x;
  float pn = 0.f, pd = 0.f;
#pragma unroll
  for (int k = t; k < NTI * NTJ; k += 256) {
    float2 v = *(const float2*)(part + k * 2);
    pn += v.x;
    pd += v.y;
  }
#pragma unroll
  for (int off = 1; off <= 32; off <<= 1) {
    pn += __shfl_xor(pn, off);
    pd += __shfl_xor(pd, off);
  }
  __shared__ float red[8];
  if ((t & 63) == 0) { red[(t >> 6) * 2] = pn; red[(t >> 6) * 2 + 1] = pd; }
  __syncthreads();
  if (t == 0) {
    float n = red[0] + red[2] + red[4] + red[6];
    float d = red[1] + red[3] + red[5] + red[7];
    out[0] = n / d;
  }
}

extern "C" void kernel_launch(void* const* d_in, const int* in_sizes, int n_in,
                              void* d_out, int out_size, void* d_ws, size_t ws_size,
                              hipStream_t stream)
{
  const float* zx = (const float*)d_in[0];
  const float* zy = (const float*)d_in[1];
  float* out = (float*)d_out;

  char* ws = (char*)d_ws;
  float* part    = (float*)(ws + 0);            // 1024*2 f32 = 8 KB
  float* rs_part = (float*)(ws + (64  << 10));  // [32][2048] f32 = 256 KB
  float* cs_part = (float*)(ws + (320 << 10));  // [32][2048] f32 = 256 KB
  __half* s_buf  = (__half*)(ws + (576 << 10)); // 8 MiB fp16

  dim3 grid(NTJ, NTI), block(256);
  k1_dist   <<<grid, block, 0, stream>>>(zx, zy, s_buf, rs_part, cs_part);
  k2_combine<<<grid, block, 0, stream>>>(s_buf, rs_part, cs_part, part);
  k3_out    <<<dim3(1), block, 0, stream>>>(part, out);
}

// Round 14
// 30.731 us; speedup vs baseline: 1.2918x; 1.0019x over previous
//
#include <hip/hip_runtime.h>
#include <hip/hip_fp16.h>

#define NROWS 2048
#define MCOLS 2048
#define DDIM  64
#define NDP   (DDIM / 2)   // 32 packed d-pairs
#define TILE  64
#define NTI   32
#define NTJ   32

// No-max softmax: s row/col maxima ~ -50 (64-d Gaussian L1), exp(-58)=6e-26
// >> f32 denormal; 1/sum <= 5e34 < f32 max. exp(s) directly, no max pass.
// Distances accumulated in packed fp16 (verified absmax 0.0 at R13); s~ used
// by BOTH k1 stats and k2 combine -> bit-consistent softmax.

// ============================================================================
// K1: 64x64 tile, 4x4 per thread, packed-fp16 inner loop over 32 d-pairs.
// Stores s~ (8 MiB) + per-tile row/col exp-sum partials.  (R13-identical)
//   rs_part: [NTJ][NROWS]   cs_part: [NTI][MCOLS]
// ============================================================================
__global__ __launch_bounds__(256) void k1_dist(
    const float* __restrict__ zx, const float* __restrict__ zy,
    __half* __restrict__ s_out,
    float* __restrict__ rs_part, float* __restrict__ cs_part)
{
  __shared__ __half2 sX[NDP][TILE];   // [dp][i]  8 KB
  __shared__ __half2 sY[NDP][TILE];   // [dp][j]  8 KB
  __shared__ float   csw[4][TILE];    // 1 KB

  const int bi = blockIdx.y, bj = blockIdx.x;
  const int t  = threadIdx.x;
  const int lid = t & 63, wv = t >> 6;
  const int i0 = (t >> 4) << 2;
  const int j0 = (t & 15) << 2;

  // ---- stage (transposed, fp16-packed d-pairs) ----
  {
    int r  = t & 63;
    int d0 = (t >> 6) << 2;
    const float* zxp = zx + (size_t)(bi * TILE + r) * DDIM;
    const float* zyp = zy + (size_t)(bj * TILE + r) * DDIM;
#pragma unroll
    for (int q = 0; q < 4; ++q) {
      int d = d0 + 16 * q;
      float4 xv = *(const float4*)(zxp + d);
      float4 yv = *(const float4*)(zyp + d);
      sX[(d >> 1) + 0][r] = __floats2half2_rn(xv.x, xv.y);
      sX[(d >> 1) + 1][r] = __floats2half2_rn(xv.z, xv.w);
      sY[(d >> 1) + 0][r] = __floats2half2_rn(yv.x, yv.y);
      sY[(d >> 1) + 1][r] = __floats2half2_rn(yv.z, yv.w);
    }
  }
  __syncthreads();

  // ---- distances: packed fp16, 2 ds_read_b128 + 48 pk-VALU per d-pair ----
  __half2 acc2[4][4];
#pragma unroll
  for (int a = 0; a < 4; ++a)
#pragma unroll
    for (int b = 0; b < 4; ++b)
      acc2[a][b] = __floats2half2_rn(0.f, 0.f);

#pragma unroll 8
  for (int dp = 0; dp < NDP; ++dp) {
    uint4 ux = *(const uint4*)&sX[dp][i0];
    uint4 uy = *(const uint4*)&sY[dp][j0];
    __half2 xr[4] = { *(const __half2*)&ux.x, *(const __half2*)&ux.y,
                      *(const __half2*)&ux.z, *(const __half2*)&ux.w };
    __half2 yc[4] = { *(const __half2*)&uy.x, *(const __half2*)&uy.y,
                      *(const __half2*)&uy.z, *(const __half2*)&uy.w };
#pragma unroll
    for (int a = 0; a < 4; ++a)
#pragma unroll
      for (int b = 0; b < 4; ++b)
        acc2[a][b] = __hadd2(acc2[a][b], __habs2(__hsub2(xr[a], yc[b])));
  }

  // ---- s~ = -(lo+hi) in fp16; store; exp for stats ----
  float E[4][4];
#pragma unroll
  for (int a = 0; a < 4; ++a) {
    __half sh[4];
#pragma unroll
    for (int b = 0; b < 4; ++b) {
      sh[b] = __hneg(__hadd(__low2half(acc2[a][b]), __high2half(acc2[a][b])));
      E[a][b] = __expf(__half2float(sh[b]));
    }
    __half2 p01 = __halves2half2(sh[0], sh[1]);
    __half2 p23 = __halves2half2(sh[2], sh[3]);
    uint2 u;
    u.x = *(const unsigned*)&p01;
    u.y = *(const unsigned*)&p23;
    *(uint2*)(s_out + (size_t)(bi * TILE + i0 + a) * MCOLS + bj * TILE + j0) = u;
  }

  // ---- row exp-sums: 16 j-lanes (bits 0..3) cover one tile-row ----
  {
    float es[4];
#pragma unroll
    for (int a = 0; a < 4; ++a)
      es[a] = (E[a][0] + E[a][1]) + (E[a][2] + E[a][3]);
#pragma unroll
    for (int off = 1; off <= 8; off <<= 1)
#pragma unroll
      for (int a = 0; a < 4; ++a)
        es[a] += __shfl_xor(es[a], off);
    if ((lid & 15) == 0) {
#pragma unroll
      for (int a = 0; a < 4; ++a)
        rs_part[bj * NROWS + bi * TILE + i0 + a] = es[a];
    }
  }

  // ---- col exp-sums: lane bits 4..5, then LDS across 4 waves ----
  {
    float ce[4];
#pragma unroll
    for (int b = 0; b < 4; ++b)
      ce[b] = (E[0][b] + E[1][b]) + (E[2][b] + E[3][b]);
#pragma unroll
    for (int off = 16; off <= 32; off <<= 1)
#pragma unroll
      for (int b = 0; b < 4; ++b)
        ce[b] += __shfl_xor(ce[b], off);
    if (lid < 16) {
#pragma unroll
      for (int b = 0; b < 4; ++b)
        csw[wv][lid * 4 + b] = ce[b];
    }
    __syncthreads();
    if (t < TILE) {
      int j = t;
      cs_part[bi * MCOLS + bj * TILE + j] =
          (csw[0][j] + csw[1][j]) + (csw[2][j] + csw[3][j]);
    }
  }
}

// ============================================================================
// K2: per-block stats-sum + reload s~ tile (2x8 microtile, uint4 loads)
//     + combine -> one (pn,pd) pair per block. No atomics, no fences.
// ============================================================================
__global__ __launch_bounds__(256) void k2_combine(
    const __half* __restrict__ s_in,
    const float* __restrict__ rs_part, const float* __restrict__ cs_part,
    float* __restrict__ part /* [NTI*NTJ][2] */)
{
  __shared__ float l_rinv[TILE];
  __shared__ float l_cinv[TILE];
  __shared__ float red[8];

  int bi = blockIdx.y, bj = blockIdx.x;
  int t  = threadIdx.x;
  int lid = t & 63, wv = t >> 6;

  // ---- plain sums of 32 partials for the 64 rows + 64 cols we need ----
  if (t < 64) {
    int i = bi * TILE + t;
    float S = 0.f;
#pragma unroll
    for (int tj = 0; tj < NTJ; ++tj) S += rs_part[tj * NROWS + i];
    l_rinv[t] = 1.f / S;
  } else if (t < 128) {
    int c = t - 64;
    int j = bj * TILE + c;
    float S = 0.f;
#pragma unroll
    for (int ti = 0; ti < NTI; ++ti) S += cs_part[ti * MCOLS + j];
    l_cinv[c] = 1.f / S;
  }
  __syncthreads();

  // ---- 2 rows x 8 cols per thread; two 16B loads ----
  const int i0 = (t >> 3) << 1;   // 0..62, 2 rows
  const int j0 = (t & 7) << 3;    // 0..56, 8 cols

  float sv[2][8];
  {
    const __half* base = s_in + (size_t)(bi * TILE + i0) * MCOLS + bj * TILE + j0;
#pragma unroll
    for (int a = 0; a < 2; ++a) {
      uint4 u = *(const uint4*)(base + (size_t)a * MCOLS);
      const unsigned uu[4] = {u.x, u.y, u.z, u.w};
#pragma unroll
      for (int p = 0; p < 4; ++p) {
        float2 f = __half22float2(*(const __half2*)&uu[p]);
        sv[a][2*p]   = f.x;
        sv[a][2*p+1] = f.y;
      }
    }
  }
  float rv[2], cv[8];
#pragma unroll
  for (int a = 0; a < 2; ++a) rv[a] = l_rinv[i0 + a];
#pragma unroll
  for (int b = 0; b < 8; ++b) cv[b] = l_cinv[j0 + b];

  float pn = 0.f, pd = 0.f;
#pragma unroll
  for (int a = 0; a < 2; ++a)
#pragma unroll
    for (int b = 0; b < 8; ++b) {
      float E  = __expf(sv[a][b]);
      float av = E * rv[a];
      float bv = E * cv[b];
      float w  = av + bv - av * bv;
      pn += w * sv[a][b];
      pd += w;
    }
#pragma unroll
  for (int off = 1; off <= 32; off <<= 1) {
    pn += __shfl_xor(pn, off);
    pd += __shfl_xor(pd, off);
  }
  if (lid == 0) { red[wv * 2] = pn; red[wv * 2 + 1] = pd; }
  __syncthreads();
  if (t == 0) {
    int bid = bi * NTJ + bj;
    float2 p;
    p.x = red[0] + red[2] + red[4] + red[6];
    p.y = red[1] + red[3] + red[5] + red[7];
    *(float2*)(part + bid * 2) = p;
  }
}

// ============================================================================
// K3: deterministic reduce of 1024 (pn,pd) pairs -> out scalar.
// ============================================================================
__global__ __launch_bounds__(256) void k3_out(
    const float* __restrict__ part, float* __restrict__ out)
{
  int t = threadIdx.x;
  float pn = 0.f, pd = 0.f;
#pragma unroll
  for (int k = t; k < NTI * NTJ; k += 256) {
    float2 v = *(const float2*)(part + k * 2);
    pn += v.x;
    pd += v.y;
  }
#pragma unroll
  for (int off = 1; off <= 32; off <<= 1) {
    pn += __shfl_xor(pn, off);
    pd += __shfl_xor(pd, off);
  }
  __shared__ float red[8];
  if ((t & 63) == 0) { red[(t >> 6) * 2] = pn; red[(t >> 6) * 2 + 1] = pd; }
  __syncthreads();
  if (t == 0) {
    float n = red[0] + red[2] + red[4] + red[6];
    float d = red[1] + red[3] + red[5] + red[7];
    out[0] = n / d;
  }
}

extern "C" void kernel_launch(void* const* d_in, const int* in_sizes, int n_in,
                              void* d_out, int out_size, void* d_ws, size_t ws_size,
                              hipStream_t stream)
{
  const float* zx = (const float*)d_in[0];
  const float* zy = (const float*)d_in[1];
  float* out = (float*)d_out;

  char* ws = (char*)d_ws;
  float* part    = (float*)(ws + 0);            // 1024*2 f32 = 8 KB
  float* rs_part = (float*)(ws + (64  << 10));  // [32][2048] f32 = 256 KB
  float* cs_part = (float*)(ws + (320 << 10));  // [32][2048] f32 = 256 KB
  __half* s_buf  = (__half*)(ws + (576 << 10)); // 8 MiB fp16

  dim3 grid(NTJ, NTI), block(256);
  k1_dist   <<<grid, block, 0, stream>>>(zx, zy, s_buf, rs_part, cs_part);
  k2_combine<<<grid, block, 0, stream>>>(s_buf, rs_part, cs_part, part);
  k3_out    <<<dim3(1), block, 0, stream>>>(part, out);
}